// Round 1
// 786.886 us; speedup vs baseline: 1.0338x; 1.0338x over previous
//
#include <hip/hip_runtime.h>
#include <cstdint>
#include <cmath>

#define NB 64
#define NS 2048
#define NR 1024
#define NH 512
#define SC 32              // s-chunks per batch in fused kernel
#define SCHUNK (NS / SC)   // 64 rows per chunk

__device__ __forceinline__ float waveReduceSum(float v) {
    #pragma unroll
    for (int off = 32; off > 0; off >>= 1) v += __shfl_down(v, off, 64);
    return v;
}

__device__ __forceinline__ float fast_tanh(float x) {
    // tanh(x) = (e^{2x}-1)/(e^{2x}+1); clamp so exp never overflows.
    float cx = fminf(fmaxf(x, -15.f), 15.f);
    float e = __expf(2.f * cx);
    return __fdividef(e - 1.f, e + 1.f);
}

// ---------------- Kernel 1: att_h[b,o] = sum_k h[b,k]*W[o,k] + bias[o] ----------------
__global__ __launch_bounds__(256) void k_atth(
    const float* __restrict__ h, const float* __restrict__ W,
    const float* __restrict__ bias, float* __restrict__ att_h)
{
    const int o = blockIdx.x;  // 0..NH-1
    __shared__ float wsh[NR];
    for (int i = threadIdx.x; i < NR; i += 256) wsh[i] = W[(size_t)o * NR + i];
    __syncthreads();
    const int wave = threadIdx.x >> 6, lane = threadIdx.x & 63;
    const float4* w4 = (const float4*)wsh;
    const float bo = bias[o];
    for (int b = wave; b < NB; b += 4) {
        const float4* h4 = (const float4*)(h + (size_t)b * NR);
        float acc = 0.f;
        #pragma unroll
        for (int i = 0; i < NR / 4 / 64; ++i) {  // 4 iters
            float4 a = h4[lane + i * 64];
            float4 w = w4[lane + i * 64];
            acc += a.x * w.x + a.y * w.y + a.z * w.z + a.w * w.w;
        }
        acc = waveReduceSum(acc);
        if (lane == 0) att_h[b * NH + o] = acc + bo;
    }
}

// ---------------- Kernel 2 (fused): per (b, s-chunk) block ----------------------------
// Phase 1: e_s = exp(score_s) for unmasked rows of the chunk -> LDS (no global weights).
// Phase 2: partial[b,c,r] = sum_s e_s * att_feats[b,s,r]  (deterministic stores).
// Also writes esums[b,c] = sum_s e_s. b_alpha cancels in the renormalized ratio; scores
// are O(1) so no max-subtraction needed (verified absmax 1.2e-4 in prior structure).
__global__ __launch_bounds__(256) void k_fused(
    const float* __restrict__ p, const float* __restrict__ att_h,
    const float* __restrict__ w_alpha, const int* __restrict__ masks,
    const float* __restrict__ feats, float* __restrict__ partial,
    float* __restrict__ esums)
{
    const int b  = blockIdx.x >> 5;   // SC = 32
    const int sc = blockIdx.x & 31;
    const int s0 = sc * SCHUNK;
    const int wave = threadIdx.x >> 6, lane = threadIdx.x & 63;
    __shared__ float ah[NH], wa[NH];
    __shared__ float cw[SCHUNK];
    __shared__ int   cidx[SCHUNK];
    __shared__ int   nnz_s;
    for (int i = threadIdx.x; i < NH; i += 256) {
        ah[i] = att_h[b * NH + i];
        wa[i] = w_alpha[i];
    }
    // compact non-masked rows (wave 0, 64 rows = 64 lanes)
    if (threadIdx.x < 64) {
        bool on = (masks[b * NS + s0 + threadIdx.x] != 0);
        unsigned long long m = __ballot(on);
        if (on) {
            int my = (int)__popcll(m & ((1ull << threadIdx.x) - 1ull));
            cidx[my] = threadIdx.x;
        }
        if (threadIdx.x == 0) nnz_s = (int)__popcll(m);
    }
    __syncthreads();
    const int nnz = nnz_s;
    const float4* ah4 = (const float4*)ah;
    const float4* wa4 = (const float4*)wa;

    // ---- Phase 1: scores -> cw[] ----
    for (int i = wave; i < nnz; i += 4) {          // branch-free over compacted rows
        const int s = s0 + cidx[i];
        const float4* p4 = (const float4*)(p + ((size_t)b * NS + s) * NH);
        float4 x0 = p4[lane];
        float4 x1 = p4[lane + 64];
        float4 a0 = ah4[lane],      a1 = ah4[lane + 64];
        float4 w0 = wa4[lane],      w1 = wa4[lane + 64];
        float acc = 0.f;
        acc += fast_tanh(x0.x + a0.x) * w0.x;
        acc += fast_tanh(x0.y + a0.y) * w0.y;
        acc += fast_tanh(x0.z + a0.z) * w0.z;
        acc += fast_tanh(x0.w + a0.w) * w0.w;
        acc += fast_tanh(x1.x + a1.x) * w1.x;
        acc += fast_tanh(x1.y + a1.y) * w1.y;
        acc += fast_tanh(x1.z + a1.z) * w1.z;
        acc += fast_tanh(x1.w + a1.w) * w1.w;
        acc = waveReduceSum(acc);
        if (lane == 0) cw[i] = __expf(fminf(acc, 60.f));  // paranoia clamp
    }
    __syncthreads();

    // per-chunk esum (wave 0; nnz <= 64) -> deterministic store, no atomics
    if (threadIdx.x < 64) {
        float e = (threadIdx.x < nnz) ? cw[threadIdx.x] : 0.f;
        e = waveReduceSum(e);
        if (threadIdx.x == 0) esums[b * SC + sc] = e;
    }

    // ---- Phase 2: weighted sum of feats rows, 4 loads in flight ----
    const float4* f4 = (const float4*)(feats + ((size_t)b * NS + s0) * NR);
    float4 acc = make_float4(0.f, 0.f, 0.f, 0.f);
    int i = 0;
    for (; i + 4 <= nnz; i += 4) {
        const float w0 = cw[i], w1 = cw[i + 1], w2 = cw[i + 2], w3 = cw[i + 3];
        const float4 v0 = f4[(size_t)cidx[i    ] * 256 + threadIdx.x];
        const float4 v1 = f4[(size_t)cidx[i + 1] * 256 + threadIdx.x];
        const float4 v2 = f4[(size_t)cidx[i + 2] * 256 + threadIdx.x];
        const float4 v3 = f4[(size_t)cidx[i + 3] * 256 + threadIdx.x];
        acc.x += w0 * v0.x + w1 * v1.x + w2 * v2.x + w3 * v3.x;
        acc.y += w0 * v0.y + w1 * v1.y + w2 * v2.y + w3 * v3.y;
        acc.z += w0 * v0.z + w1 * v1.z + w2 * v2.z + w3 * v3.z;
        acc.w += w0 * v0.w + w1 * v1.w + w2 * v2.w + w3 * v3.w;
    }
    for (; i < nnz; ++i) {
        const float w = cw[i];
        const float4 v = f4[(size_t)cidx[i] * 256 + threadIdx.x];
        acc.x += w * v.x; acc.y += w * v.y; acc.z += w * v.z; acc.w += w * v.w;
    }
    float4* o = (float4*)(partial + (size_t)(b * SC + sc) * NR);
    o[threadIdx.x] = acc;   // plain store, no atomics, no memset needed
}

// ---------------- Kernel 3: out[b,r] = sum_c partial[b,c,r] / sum_c esums[b,c] --------
__global__ __launch_bounds__(64) void k_reduce(
    const float* __restrict__ partial, const float* __restrict__ esums,
    float* __restrict__ out)
{
    const int b    = blockIdx.x >> 2;   // 4 blocks per batch
    const int q    = blockIdx.x & 3;
    const int lane = threadIdx.x;       // 64 threads = 1 wave
    float e = (lane < SC) ? esums[b * SC + lane] : 0.f;
    float T = waveReduceSum(e);
    T = __shfl(T, 0, 64);
    const float invT = 1.0f / T;
    const int r4 = q * 64 + lane;       // float4 index within the 1024-float row
    const float4* p4 = (const float4*)(partial + (size_t)b * SC * NR);
    float4 acc = make_float4(0.f, 0.f, 0.f, 0.f);
    #pragma unroll 8
    for (int c = 0; c < SC; ++c) {
        float4 v = p4[(size_t)c * 256 + r4];
        acc.x += v.x; acc.y += v.y; acc.z += v.z; acc.w += v.w;
    }
    float4 r;
    r.x = acc.x * invT; r.y = acc.y * invT; r.z = acc.z * invT; r.w = acc.w * invT;
    ((float4*)(out + (size_t)b * NR))[r4] = r;
}

extern "C" void kernel_launch(void* const* d_in, const int* in_sizes, int n_in,
                              void* d_out, int out_size, void* d_ws, size_t ws_size,
                              hipStream_t stream) {
    const float* h        = (const float*)d_in[0];
    const float* feats    = (const float*)d_in[1];
    const float* p        = (const float*)d_in[2];
    const int*   masks    = (const int*)d_in[3];
    const float* W        = (const float*)d_in[4];
    const float* bh       = (const float*)d_in[5];
    const float* w_alpha  = (const float*)d_in[6];
    // d_in[7] = b_alpha: cancels in softmax renormalization — unused.
    float* out = (float*)d_out;

    float* ws      = (float*)d_ws;
    float* att_h   = ws;                          // NB*NH          = 32768 floats
    float* partial = att_h + NB * NH;             // NB*SC*NR       = 2M floats (8 MB)
    float* esums   = partial + (size_t)NB * SC * NR;  // NB*SC      = 2048 floats

    k_atth  <<<NH,      256, 0, stream>>>(h, W, bh, att_h);
    k_fused <<<NB * SC, 256, 0, stream>>>(p, att_h, w_alpha, masks, feats, partial, esums);
    k_reduce<<<NB * 4,  64,  0, stream>>>(partial, esums, out);
}